// Round 1
// baseline (281.289 us; speedup 1.0000x reference)
//
#include <hip/hip_runtime.h>

// GroupTokenizer: y [B,T,C] f32, edges [C,K] f32 -> labels [B,T,C] (as f32), reg [B,T,C,K] f32.
// B=32 T=4096 C=8 K=64. N = B*T*C = 1048576. Output = 272.6 MB -> streaming-store bound.
//
// R5: decouple the store stream from the compute. Previous version threaded every
// float4 store behind 2 ds_bpermutes <- label/delta <- 7-deep dependent LDS binary
// search, so the write pipe idled during each wave's front-end (~3 TB/s effective vs
// 6.27 TB/s that the rocclr fill sustains on this same buffer). Now: blast the 16 KB
// tile with dependence-free -1 stores (memset-shaped), overlap the binary search with
// the drain, then scatter ONE dword/lane of delta into the just-written lines (still
// dirty in this CU's own XCD L2 -> merges, no extra HBM traffic). WAW ordered by
// s_waitcnt vmcnt(0). No shuffles, no cndmask epilogue.
#define N_ELEM (32 * 4096 * 8)
#define CCH 8
#define KB 64

typedef float vfloat4 __attribute__((ext_vector_type(4)));

__global__ __launch_bounds__(256) void group_tokenizer_kernel(
    const float* __restrict__ y,
    const float* __restrict__ le,
    const float* __restrict__ re,
    float* __restrict__ out,
    int ngroups) {
  // Edges in LDS, stride K+1=65 so bank = (c + k) % 32 (distinct across the 8 channels;
  // same-channel lanes hit identical addresses -> broadcast, free).
  __shared__ float ls[CCH][KB + 1];
  __shared__ float rs[CCH][KB + 1];
  const int tid = threadIdx.x;
  for (int t = tid; t < CCH * KB; t += blockDim.x) {
    ls[t >> 6][t & 63] = le[t];
    rs[t >> 6][t & 63] = re[t];
  }
  __syncthreads();

  const int lane = tid & 63;
  const int wid = tid >> 6;
  const int wavesPerBlock = blockDim.x >> 6;
  const int gwave = blockIdx.x * wavesPerBlock + wid;
  const int nwaves = gridDim.x * wavesPerBlock;

  const vfloat4 neg1 = {-1.0f, -1.0f, -1.0f, -1.0f};

  for (int g = gwave; g < ngroups; g += nwaves) {
    const int e = g * 64 + lane;           // element index (lane-contiguous)
    const float yv = y[e];                 // independent of stores; issues early

    // Bulk phase: wave tile = 64 elems * 64 bins = 16 KB contiguous. 16 fully-coalesced,
    // dependence-free float4 stores of -1 (1 KB/instr/wave, full lines) -- identical
    // access shape to the 6.27 TB/s fill kernel.
    float* regbase = out + (size_t)N_ELEM + (size_t)g * (64 * KB);
    vfloat4* regv = (vfloat4*)regbase;
#pragma unroll
    for (int j = 0; j < 16; ++j) {
      regv[(j << 6) + lane] = neg1;
    }

    // Compute phase (overlaps the store drain): binary search in LDS.
    const int c = e & (CCH - 1);           // e % 8 == lane % 8 (group base divisible by 64)
    const float* lr = ls[c];
    const float* rr = rs[c];

    // lower_bound on r: first k with yv < r[k]. 65 possible answers (0..64) ->
    // SEVEN branchless steps (6 left a size-1 interval untested -> earlier absmax bug).
    int lo = 0, hi = KB;
#pragma unroll
    for (int it = 0; it < 7; ++it) {
      const int mid = (lo + hi) >> 1;
      const bool cond = yv < rr[mid];
      hi = cond ? mid : hi;
      lo = cond ? lo : mid + 1;
    }
    // in_bin[lo] iff yv >= l[lo]; otherwise no bin anywhere -> label K-1.
    // (lo==KB read is safe: arrays padded to KB+1.)
    const int label = (lo < KB && yv >= lr[lo]) ? lo : (KB - 1);

    const float left = lr[label];
    const float right = rr[label];
    const float width = fmaxf(right - left, 1e-12f);
    float delta = (yv - left) / width;
    delta = fminf(fmaxf(delta, 0.0f), 1.0f);

    // labels output (as float), coalesced 4B/lane.
    out[e] = (float)label;

    // Order the delta scatter after this wave's -1 tile stores (same-wave same-address
    // WAW). After vmcnt(0) the -1 writes are at this XCD's L2 (point of coherence);
    // the scatter below hits the same dirty lines and merges there.
    asm volatile("s_waitcnt vmcnt(0)" ::: "memory");

    // Sparse phase: one dword per lane at [elem=lane][k=label]. 64 scattered dwords
    // across the wave's own 16 KB tile -> all L2 hits, negligible issue cost.
    regbase[(lane << 6) + label] = delta;
  }
}

extern "C" void kernel_launch(void* const* d_in, const int* in_sizes, int n_in,
                              void* d_out, int out_size, void* d_ws, size_t ws_size,
                              hipStream_t stream) {
  const float* y = (const float*)d_in[0];
  const float* le = (const float*)d_in[1];
  const float* re = (const float*)d_in[2];
  float* out = (float*)d_out;

  const int n = in_sizes[0];          // 1048576
  const int ngroups = n / 64;         // 16384 wave-tiles
  const int wavesPerBlock = 4;        // 256 threads
  const int groupsPerWave = 2;        // persistent-ish: amortize prologue, keep 8 blk/CU
  const int blocks =
      (ngroups + wavesPerBlock * groupsPerWave - 1) / (wavesPerBlock * groupsPerWave);  // 2048

  group_tokenizer_kernel<<<blocks, 256, 0, stream>>>(y, le, re, out, ngroups);
}